// Round 1
// 120.081 us; speedup vs baseline: 1.0081x; 1.0081x over previous
//
#include <hip/hip_runtime.h>
#include <math.h>

#define BB 4
#define NN 100000
#define KK 128
#define HB 256   // threads per block
#define HH 4     // hits per thread: one LDS broadcast feeds HH pairs
#define GX ((NN + HB * HH - 1) / (HB * HH))   // 98 blocks in x
#define NBLK (GX * BB)                         // 392 k_main blocks

// ws layout:
// [0,    4096): unsigned long long packed[B*K]   key = bits(clip(beta))<<32 | ~n
// [4096, 4096 + NBLK*32): float part[NBLK][8]    per-block partials (no atomics)
//   comp: 0 att, 1 rep, 2 noise_beta, 3 noise_cnt, 4 p_sum, 5 e, 6 pos, 7 time

typedef float v2f __attribute__((ext_vector_type(2)));

#if __has_builtin(__builtin_elementwise_fma)
#define FMA2(a, b, c) __builtin_elementwise_fma((a), (b), (c))
#else
static __device__ __forceinline__ v2f fma2_(v2f a, v2f b, v2f c) {
    v2f r; r.x = __builtin_fmaf(a.x, b.x, c.x); r.y = __builtin_fmaf(a.y, b.y, c.y);
    return r;
}
#define FMA2 fma2_
#endif

#if __has_builtin(__builtin_elementwise_max)
#define MAX2(a, b) __builtin_elementwise_max((a), (b))
#else
static __device__ __forceinline__ v2f max2_(v2f a, v2f b) {
    v2f r; r.x = fmaxf(a.x, b.x); r.y = fmaxf(a.y, b.y);
    return r;
}
#define MAX2 max2_
#endif

__device__ __forceinline__ float clipb(float b) {
    return fminf(fmaxf(b, 1e-4f), 1.0f - 1e-4f);
}

// argmax over q == argmax over clip(beta) (monotone). Positive-float bits are
// order-preserving; ~n breaks ties toward smaller n (jnp.argmax semantics).
__global__ void k_argmax(const float* __restrict__ beta,
                         const int* __restrict__ tidx,
                         unsigned long long* __restrict__ packed) {
    int b = blockIdx.y;
    __shared__ unsigned long long smax[KK];
    for (int t = threadIdx.x; t < KK; t += blockDim.x) smax[t] = 0ULL;
    __syncthreads();
    const float* betab = beta + b * NN;
    const int*   tib   = tidx + b * NN;
    for (int n = blockIdx.x * blockDim.x + threadIdx.x; n < NN;
         n += gridDim.x * blockDim.x) {
        int obj = tib[n] - 1;
        if (obj >= 0) {
            unsigned hi = __float_as_uint(clipb(betab[n]));
            unsigned long long key = ((unsigned long long)hi << 32) |
                                     (unsigned long long)(0xFFFFFFFFu - (unsigned)n);
            atomicMax(&smax[obj], key);
        }
    }
    __syncthreads();
    for (int t = threadIdx.x; t < KK; t += blockDim.x) {
        unsigned long long v = smax[t];
        if (v) atomicMax(&packed[b * KK + t], v);
    }
}

__global__ void __launch_bounds__(HB) k_main(
    const float*  __restrict__ beta, const float2* __restrict__ cc,
    const float*  __restrict__ pe,   const float2* __restrict__ pp,
    const float*  __restrict__ pt,   const float*  __restrict__ te,
    const float2* __restrict__ tp,   const float*  __restrict__ tt,
    const int*    __restrict__ tidx,
    const unsigned long long* __restrict__ packed,
    float* __restrict__ part) {
    int b = blockIdx.y;
    // SoA condensation points: pair-readable as v2f (ds_read_b64 broadcast)
    __shared__ v2f sox[KK / 2];   // x_alpha
    __shared__ v2f soy[KK / 2];   // y_alpha
    __shared__ v2f soq[KK / 2];   // q_alpha * exf
    __shared__ float sred[4][8];
    float* sax = (float*)sox;
    float* say = (float*)soy;
    float* saq = (float*)soq;

    // self-gather: decode condensation points from packed[] (512 B, L2-hot)
    if (threadIdx.x < KK) {
        unsigned long long v = packed[b * KK + threadIdx.x];
        float x = 0.f, y = 0.f, qz = 0.f;
        if (v) {
            unsigned n = 0xFFFFFFFFu - (unsigned)(v & 0xFFFFFFFFu);
            float ba = __uint_as_float((unsigned)(v >> 32));  // clip(beta_alpha)
            float at = atanhf(ba);
            float2 c = cc[b * NN + (int)n];
            x = c.x; y = c.y; qz = at * at + 0.5f;            // Q_MIN = 0.5
        }
        sax[threadIdx.x] = x;
        say[threadIdx.x] = y;
        saq[threadIdx.x] = qz;
    }

    int base = blockIdx.x * (HB * HH) + threadIdx.x;
    bool vv[HH]; int ii[HH]; float2 ch[HH]; float rp[HH];
    v2f cx2[HH], cy2[HH];
    #pragma unroll
    for (int h = 0; h < HH; ++h) {
        int n = base + h * HB;
        vv[h] = n < NN;
        ii[h] = b * NN + (vv[h] ? n : 0);
        ch[h] = cc[ii[h]];
        cx2[h].x = ch[h].x; cx2[h].y = ch[h].x;
        cy2[h].x = ch[h].y; cy2[h].y = ch[h].y;
        rp[h] = 0.f;
    }
    __syncthreads();

    const v2f eps2 = {1e-12f, 1e-12f};
    const v2f one2 = {1.0f, 1.0f};
    const v2f zero2 = {0.0f, 0.0f};

    // two objects per iteration: packed-f32 (v_pk_*) dual-rate VALU.
    // per-element op sequence identical to scalar version; rp accumulated in
    // ascending-k order with scalar fmas -> bit-identical partials.
    #pragma unroll 2
    for (int k2 = 0; k2 < KK / 2; ++k2) {
        v2f ox = sox[k2], oy = soy[k2], oq = soq[k2];   // uniform -> broadcast
        #pragma unroll
        for (int h = 0; h < HH; ++h) {
            v2f dx = cx2[h] - ox;
            v2f dy = cy2[h] - oy;
            v2f s  = FMA2(dx, dx, FMA2(dy, dy, eps2));
            v2f d;
            d.x = __builtin_amdgcn_sqrtf(s.x);          // raw v_sqrt_f32
            d.y = __builtin_amdgcn_sqrtf(s.y);
            v2f r = MAX2(one2 - d, zero2);
            rp[h] = fmaf(oq.x, r.x, rp[h]);             // k = 2*k2
            rp[h] = fmaf(oq.y, r.y, rp[h]);             // k = 2*k2+1
        }
    }

    float p_att = 0.f, p_rep = 0.f, p_nb = 0.f, p_nc = 0.f;
    float p_ps = 0.f, p_e = 0.f, p_pos = 0.f, p_tm = 0.f;

    #pragma unroll
    for (int h = 0; h < HH; ++h) {
        if (!vv[h]) continue;
        int   idx = ii[h];
        float rep = rp[h];
        float bc  = clipb(beta[idx]);
        float at  = atanhf(bc);
        float at2 = at * at;
        float q   = at2 + 0.5f;
        int   ti  = tidx[idx];
        int   obj = ti - 1;

        if (obj >= 0) {                     // member: move own term rep -> att
            float ox = sax[obj], oy = say[obj], oqz = saq[obj];
            float dx = ch[h].x - ox, dy = ch[h].y - oy;
            float s = fmaf(dx, dx, fmaf(dy, dy, 1e-12f));
            float d = __builtin_amdgcn_sqrtf(s);
            rep   -= oqz * fmaxf(1.0f - d, 0.0f);
            p_att += q * (oqz * s);         // dist^2 == s (incl. 1e-12 eps)
        }
        p_rep += q * rep;

        if (ti == 0) {                      // noise hit
            p_nb += bc;
            p_nc += 1.0f;
        } else {                            // payload (beta-weighted, non-noise)
            p_ps += at2;
            float de = pe[idx] - te[idx];
            float a  = fabsf(de);
            float hb = (a <= 2.0f) ? (0.5f * de * de) : (2.0f * (a - 1.0f));
            p_e  += at2 * hb;
            float2 ppv = pp[idx], tpv = tp[idx];
            float dpx = ppv.x - tpv.x, dpy = ppv.y - tpv.y;
            p_pos += at2 * (dpx * dpx + dpy * dpy);
            float dt = pt[idx] - tt[idx];
            p_tm += at2 * dt * dt;
        }
    }

    float vals[8] = {p_att, p_rep, p_nb, p_nc, p_ps, p_e, p_pos, p_tm};
    int lane = threadIdx.x & 63, wave = threadIdx.x >> 6;
    #pragma unroll
    for (int i = 0; i < 8; ++i) {
        float v = vals[i];
        #pragma unroll
        for (int off = 32; off > 0; off >>= 1) v += __shfl_down(v, off, 64);
        if (lane == 0) sred[wave][i] = v;
    }
    __syncthreads();
    if (threadIdx.x < 8) {
        float s = sred[0][threadIdx.x] + sred[1][threadIdx.x] +
                  sred[2][threadIdx.x] + sred[3][threadIdx.x];
        part[(b * GX + blockIdx.x) * 8 + threadIdx.x] = s;   // plain store
    }
}

// single wave: reduce part[NBLK][8] + derive beta_alpha terms from packed bits
__global__ void __launch_bounds__(64) k_final(
    const float* __restrict__ part,
    const unsigned long long* __restrict__ packed,
    float* __restrict__ out) {
    int lane = threadIdx.x;

    // beta_alpha / n_obj terms straight from the packed keys (no gather)
    float nobj = 0.f, sba = 0.f;
    for (int t = lane; t < BB * KK; t += 64) {
        unsigned long long v = packed[t];
        if (v) {
            nobj += 1.f;
            sba  += 1.0f - __uint_as_float((unsigned)(v >> 32));
        }
    }
    #pragma unroll
    for (int off = 32; off > 0; off >>= 1) {
        nobj += __shfl_xor(nobj, off, 64);
        sba  += __shfl_xor(sba, off, 64);
    }

    // lane L sums component (L&7) over rows (L>>3)+8j (coalesced)
    int comp = lane & 7;
    float v = 0.f;
    for (int r = lane >> 3; r < NBLK; r += 8)
        v += part[r * 8 + comp];
    v += __shfl_xor(v, 8, 64);
    v += __shfl_xor(v, 16, 64);
    v += __shfl_xor(v, 32, 64);            // lane c (c<8) holds total of comp c
    float tot[8];
    #pragma unroll
    for (int c = 0; c < 8; ++c) tot[c] = __shfl(v, c, 64);

    if (lane == 0) {
        float inv_n  = 1.0f / (float)(BB * NN);
        float L_beta = sba / fmaxf(nobj, 1.0f) +
                       tot[2] / fmaxf(tot[3], 1.0f);         // S_B = 1
        float p_sum  = fmaxf(tot[4], 1e-6f);
        out[0] = tot[0] * inv_n + tot[1] * inv_n + L_beta +
                 (tot[5] + tot[6] + tot[7]) / p_sum;
    }
}

extern "C" void kernel_launch(void* const* d_in, const int* in_sizes, int n_in,
                              void* d_out, int out_size, void* d_ws, size_t ws_size,
                              hipStream_t stream) {
    const float*  beta = (const float*)d_in[0];
    const float2* cc   = (const float2*)d_in[1];
    const float*  pe   = (const float*)d_in[2];
    const float2* pp   = (const float2*)d_in[3];
    const float*  pt   = (const float*)d_in[4];
    const float*  te   = (const float*)d_in[5];
    const float2* tp   = (const float2*)d_in[6];
    const float*  tt   = (const float*)d_in[7];
    const int*    ti   = (const int*)d_in[8];

    unsigned long long* packed = (unsigned long long*)d_ws;
    float* part = (float*)((char*)d_ws + 4096);
    float* out  = (float*)d_out;

    hipMemsetAsync(packed, 0, 4096, stream);   // only packed[] needs zeroing
    k_argmax<<<dim3(64, BB), 256, 0, stream>>>(beta, ti, packed);  // 256 blocks = 1/CU
    k_main<<<dim3(GX, BB), HB, 0, stream>>>(
        beta, cc, pe, pp, pt, te, tp, tt, ti, packed, part);
    k_final<<<1, 64, 0, stream>>>(part, packed, out);
}

// Round 2
// 118.437 us; speedup vs baseline: 1.0221x; 1.0139x over previous
//
#include <hip/hip_runtime.h>
#include <math.h>

#define BB 4
#define NN 100000
#define KK 128
#define HB 256   // threads per block
#define HH 7     // hits per thread
#define GX 56    // 56*256*7 = 100352 >= 100000; NBLK=224 <= 256 CUs: 1 round, balanced
#define NBLK (GX * BB)
#define PB 32    // argmax partial-blocks per batch

// ws layout (bytes):
// [0,      131072): u64 pk_part[BB][PB][KK]   per-block argmax partials (plain stores)
// [131072, 135168): u64 final_packed[BB][KK]  reduced keys (written by x==0 k_main blocks)
// [135168, 147712): float part[NBLK][8]       per-block partial sums
// [147712, 147716): uint cnt                  last-block counter (zeroed by k_argmax)
//   comp: 0 att, 1 rep, 2 noise_beta, 3 noise_cnt, 4 p_sum, 5 e, 6 pos, 7 time

typedef float v2f __attribute__((ext_vector_type(2)));

#if __has_builtin(__builtin_elementwise_fma)
#define FMA2(a, b, c) __builtin_elementwise_fma((a), (b), (c))
#else
static __device__ __forceinline__ v2f fma2_(v2f a, v2f b, v2f c) {
    v2f r; r.x = __builtin_fmaf(a.x, b.x, c.x); r.y = __builtin_fmaf(a.y, b.y, c.y);
    return r;
}
#define FMA2 fma2_
#endif

#if __has_builtin(__builtin_elementwise_max)
#define MAX2(a, b) __builtin_elementwise_max((a), (b))
#else
static __device__ __forceinline__ v2f max2_(v2f a, v2f b) {
    v2f r; r.x = fmaxf(a.x, b.x); r.y = fmaxf(a.y, b.y);
    return r;
}
#define MAX2 max2_
#endif

__device__ __forceinline__ float clipb(float b) {
    return fminf(fmaxf(b, 1e-4f), 1.0f - 1e-4f);
}

// argmax over q == argmax over clip(beta) (monotone). Positive-float bits are
// order-preserving; ~n breaks ties toward smaller n (jnp.argmax semantics).
__device__ __forceinline__ unsigned long long mkkey(float bf, unsigned n) {
    unsigned hi = __float_as_uint(clipb(bf));
    return ((unsigned long long)hi << 32) |
           (unsigned long long)(0xFFFFFFFFu - n);
}

// Per-block LDS argmax -> plain-store partials. No memset needed, no global
// atomics. Also zeroes the last-block counter for k_main (stream order
// guarantees this lands before any k_main increment).
__global__ void __launch_bounds__(256) k_argmax(
    const float4* __restrict__ beta4, const int4* __restrict__ tidx4,
    unsigned long long* __restrict__ pk_part, unsigned int* __restrict__ cnt) {
    int b = blockIdx.y;
    __shared__ unsigned long long smax[KK];
    for (int t = threadIdx.x; t < KK; t += 256) smax[t] = 0ULL;
    if (blockIdx.x == 0 && b == 0 && threadIdx.x == 0) *cnt = 0u;
    __syncthreads();
    const float4* b4 = beta4 + (size_t)b * (NN / 4);
    const int4*   t4 = tidx4 + (size_t)b * (NN / 4);
    for (int i = blockIdx.x * 256 + threadIdx.x; i < NN / 4; i += PB * 256) {
        float4 bv = b4[i];
        int4   tv = t4[i];
        unsigned n0 = 4u * (unsigned)i;
        if (tv.x > 0) atomicMax(&smax[tv.x - 1], mkkey(bv.x, n0));
        if (tv.y > 0) atomicMax(&smax[tv.y - 1], mkkey(bv.y, n0 + 1));
        if (tv.z > 0) atomicMax(&smax[tv.z - 1], mkkey(bv.z, n0 + 2));
        if (tv.w > 0) atomicMax(&smax[tv.w - 1], mkkey(bv.w, n0 + 3));
    }
    __syncthreads();
    if (threadIdx.x < KK)
        pk_part[((size_t)b * PB + blockIdx.x) * KK + threadIdx.x] =
            smax[threadIdx.x];
}

__global__ void __launch_bounds__(HB) k_main(
    const float*  __restrict__ beta, const float2* __restrict__ cc,
    const float*  __restrict__ pe,   const float2* __restrict__ pp,
    const float*  __restrict__ pt,   const float*  __restrict__ te,
    const float2* __restrict__ tp,   const float*  __restrict__ tt,
    const int*    __restrict__ tidx,
    const unsigned long long* __restrict__ pk_part,
    unsigned long long* __restrict__ final_packed,
    float* __restrict__ part, unsigned int* __restrict__ cnt,
    float* __restrict__ out) {
    int b = blockIdx.y;
    // SoA condensation points: pair-readable as v2f (ds_read_b64 broadcast)
    __shared__ v2f sox[KK / 2];   // x_alpha
    __shared__ v2f soy[KK / 2];   // y_alpha
    __shared__ v2f soq[KK / 2];   // q_alpha * exf
    __shared__ float sred[4][8];
    __shared__ unsigned s_last;
    float* sax = (float*)sox;
    float* say = (float*)soy;
    float* saq = (float*)soq;

    // reduce argmax partials (L2/IF-hot) -> decode condensation points
    if (threadIdx.x < KK) {
        const unsigned long long* src =
            pk_part + ((size_t)b * PB) * KK + threadIdx.x;
        unsigned long long v = 0ULL;
        #pragma unroll 8
        for (int pb = 0; pb < PB; ++pb) {
            unsigned long long u = src[(size_t)pb * KK];
            v = (u > v) ? u : v;
        }
        if (blockIdx.x == 0) final_packed[b * KK + threadIdx.x] = v;
        float x = 0.f, y = 0.f, qz = 0.f;
        if (v) {
            unsigned n = 0xFFFFFFFFu - (unsigned)(v & 0xFFFFFFFFu);
            float ba = __uint_as_float((unsigned)(v >> 32));  // clip(beta_alpha)
            float at = atanhf(ba);
            float2 c = cc[b * NN + (int)n];
            x = c.x; y = c.y; qz = at * at + 0.5f;            // Q_MIN = 0.5
        }
        sax[threadIdx.x] = x;
        say[threadIdx.x] = y;
        saq[threadIdx.x] = qz;
    }

    int base = blockIdx.x * (HB * HH) + threadIdx.x;
    bool vv[HH]; int ii[HH]; float rp[HH];
    v2f cx2[HH], cy2[HH];
    #pragma unroll
    for (int h = 0; h < HH; ++h) {
        int n = base + h * HB;
        vv[h] = n < NN;
        ii[h] = b * NN + (vv[h] ? n : 0);
        float2 c = cc[ii[h]];
        cx2[h].x = c.x; cx2[h].y = c.x;
        cy2[h].x = c.y; cy2[h].y = c.y;
        rp[h] = 0.f;
    }
    __syncthreads();

    const v2f eps2 = {1e-12f, 1e-12f};
    const v2f one2 = {1.0f, 1.0f};
    const v2f zero2 = {0.0f, 0.0f};

    // two objects per iteration: packed-f32 (v_pk_*) dual-rate VALU.
    // rp accumulated in ascending-k order with scalar fmas.
    #pragma unroll 2
    for (int k2 = 0; k2 < KK / 2; ++k2) {
        v2f ox = sox[k2], oy = soy[k2], oq = soq[k2];   // uniform -> broadcast
        #pragma unroll
        for (int h = 0; h < HH; ++h) {
            v2f dx = cx2[h] - ox;
            v2f dy = cy2[h] - oy;
            v2f s  = FMA2(dx, dx, FMA2(dy, dy, eps2));
            v2f d;
            d.x = __builtin_amdgcn_sqrtf(s.x);          // raw v_sqrt_f32
            d.y = __builtin_amdgcn_sqrtf(s.y);
            v2f r = MAX2(one2 - d, zero2);
            rp[h] = fmaf(oq.x, r.x, rp[h]);             // k = 2*k2
            rp[h] = fmaf(oq.y, r.y, rp[h]);             // k = 2*k2+1
        }
    }

    float p_att = 0.f, p_rep = 0.f, p_nb = 0.f, p_nc = 0.f;
    float p_ps = 0.f, p_e = 0.f, p_pos = 0.f, p_tm = 0.f;

    #pragma unroll
    for (int h = 0; h < HH; ++h) {
        if (!vv[h]) continue;
        int   idx = ii[h];
        float rep = rp[h];
        float bc  = clipb(beta[idx]);
        float at  = atanhf(bc);
        float at2 = at * at;
        float q   = at2 + 0.5f;
        int   ti  = tidx[idx];
        int   obj = ti - 1;

        if (obj >= 0) {                     // member: move own term rep -> att
            float ox = sax[obj], oy = say[obj], oqz = saq[obj];
            float dx = cx2[h].x - ox, dy = cy2[h].x - oy;
            float s = fmaf(dx, dx, fmaf(dy, dy, 1e-12f));
            float d = __builtin_amdgcn_sqrtf(s);
            rep   -= oqz * fmaxf(1.0f - d, 0.0f);
            p_att += q * (oqz * s);         // dist^2 == s (incl. 1e-12 eps)
        }
        p_rep += q * rep;

        if (ti == 0) {                      // noise hit
            p_nb += bc;
            p_nc += 1.0f;
        } else {                            // payload (beta-weighted, non-noise)
            p_ps += at2;
            float de = pe[idx] - te[idx];
            float a  = fabsf(de);
            float hb = (a <= 2.0f) ? (0.5f * de * de) : (2.0f * (a - 1.0f));
            p_e  += at2 * hb;
            float2 ppv = pp[idx], tpv = tp[idx];
            float dpx = ppv.x - tpv.x, dpy = ppv.y - tpv.y;
            p_pos += at2 * (dpx * dpx + dpy * dpy);
            float dt = pt[idx] - tt[idx];
            p_tm += at2 * dt * dt;
        }
    }

    float vals[8] = {p_att, p_rep, p_nb, p_nc, p_ps, p_e, p_pos, p_tm};
    int lane = threadIdx.x & 63, wave = threadIdx.x >> 6;
    #pragma unroll
    for (int i = 0; i < 8; ++i) {
        float v = vals[i];
        #pragma unroll
        for (int off = 32; off > 0; off >>= 1) v += __shfl_down(v, off, 64);
        if (lane == 0) sred[wave][i] = v;
    }
    __syncthreads();
    if (threadIdx.x < 8) {
        float s = sred[0][threadIdx.x] + sred[1][threadIdx.x] +
                  sred[2][threadIdx.x] + sred[3][threadIdx.x];
        part[(b * GX + blockIdx.x) * 8 + threadIdx.x] = s;   // plain store
    }
    __syncthreads();

    // last-block-done: release our part row, count, last block finalizes
    if (threadIdx.x == 0) {
        __threadfence();                                  // device-scope release
        unsigned prev = atomicAdd(cnt, 1u);               // device-scope
        s_last = (prev == (unsigned)(NBLK - 1)) ? 1u : 0u;
    }
    __syncthreads();
    if (s_last) {
        __threadfence();                                  // device-scope acquire
        if (threadIdx.x < 64) {
            int flane = threadIdx.x;

            // beta_alpha / n_obj terms straight from the reduced keys
            float nobj = 0.f, sba = 0.f;
            for (int t = flane; t < BB * KK; t += 64) {
                unsigned long long v = final_packed[t];
                if (v) {
                    nobj += 1.f;
                    sba  += 1.0f - __uint_as_float((unsigned)(v >> 32));
                }
            }
            #pragma unroll
            for (int off = 32; off > 0; off >>= 1) {
                nobj += __shfl_xor(nobj, off, 64);
                sba  += __shfl_xor(sba, off, 64);
            }

            // lane L sums component (L&7) over rows (L>>3)+8j (coalesced)
            int comp = flane & 7;
            float v = 0.f;
            for (int r = flane >> 3; r < NBLK; r += 8)
                v += part[r * 8 + comp];
            v += __shfl_xor(v, 8, 64);
            v += __shfl_xor(v, 16, 64);
            v += __shfl_xor(v, 32, 64);      // lane c (c<8) holds total of comp c
            float tot[8];
            #pragma unroll
            for (int c = 0; c < 8; ++c) tot[c] = __shfl(v, c, 64);

            if (flane == 0) {
                float inv_n  = 1.0f / (float)(BB * NN);
                float L_beta = sba / fmaxf(nobj, 1.0f) +
                               tot[2] / fmaxf(tot[3], 1.0f);      // S_B = 1
                float p_sum  = fmaxf(tot[4], 1e-6f);
                out[0] = tot[0] * inv_n + tot[1] * inv_n + L_beta +
                         (tot[5] + tot[6] + tot[7]) / p_sum;
            }
        }
    }
}

extern "C" void kernel_launch(void* const* d_in, const int* in_sizes, int n_in,
                              void* d_out, int out_size, void* d_ws, size_t ws_size,
                              hipStream_t stream) {
    const float*  beta = (const float*)d_in[0];
    const float2* cc   = (const float2*)d_in[1];
    const float*  pe   = (const float*)d_in[2];
    const float2* pp   = (const float2*)d_in[3];
    const float*  pt   = (const float*)d_in[4];
    const float*  te   = (const float*)d_in[5];
    const float2* tp   = (const float2*)d_in[6];
    const float*  tt   = (const float*)d_in[7];
    const int*    ti   = (const int*)d_in[8];

    unsigned long long* pk_part      = (unsigned long long*)d_ws;
    unsigned long long* final_packed = (unsigned long long*)((char*)d_ws + 131072);
    float*              part         = (float*)((char*)d_ws + 135168);
    unsigned int*       cnt          = (unsigned int*)((char*)d_ws + 147712);
    float*              out          = (float*)d_out;

    k_argmax<<<dim3(PB, BB), 256, 0, stream>>>(
        (const float4*)beta, (const int4*)ti, pk_part, cnt);
    k_main<<<dim3(GX, BB), HB, 0, stream>>>(
        beta, cc, pe, pp, pt, te, tp, tt, ti,
        pk_part, final_packed, part, cnt, out);
}

// Round 3
// 115.066 us; speedup vs baseline: 1.0521x; 1.0293x over previous
//
#include <hip/hip_runtime.h>
#include <math.h>

#define BB 4
#define NN 100000
#define KK 128
#define HB 512   // threads per block: 8 waves = 2 waves/SIMD (VALU/trans overlap)
#define HH 4     // hits per thread
#define GX 49    // 49*512*4 = 100352 >= 100000; NBLK=196 co-resident, balanced
#define NBLK (GX * BB)
#define PB 64    // argmax partial-blocks per batch (256 blocks = 1/CU)

// ws layout (bytes):
// [0,      262144): u64 pk_part[BB][PB][KK]   per-block argmax partials (plain stores)
// [262144, 266240): u64 final_packed[BB][KK]  reduced keys (written by x==0 k_main blocks)
// [266240, 272512): float part[NBLK][8]       per-block partial sums
// [272512, 272516): uint cnt                  last-block counter (zeroed by k_argmax)
//   comp: 0 att, 1 rep, 2 noise_beta, 3 noise_cnt, 4 p_sum, 5 e, 6 pos, 7 time

typedef float v2f __attribute__((ext_vector_type(2)));

#if __has_builtin(__builtin_elementwise_fma)
#define FMA2(a, b, c) __builtin_elementwise_fma((a), (b), (c))
#else
static __device__ __forceinline__ v2f fma2_(v2f a, v2f b, v2f c) {
    v2f r; r.x = __builtin_fmaf(a.x, b.x, c.x); r.y = __builtin_fmaf(a.y, b.y, c.y);
    return r;
}
#define FMA2 fma2_
#endif

#if __has_builtin(__builtin_elementwise_max)
#define MAX2(a, b) __builtin_elementwise_max((a), (b))
#else
static __device__ __forceinline__ v2f max2_(v2f a, v2f b) {
    v2f r; r.x = fmaxf(a.x, b.x); r.y = fmaxf(a.y, b.y);
    return r;
}
#define MAX2 max2_
#endif

__device__ __forceinline__ float clipb(float b) {
    return fminf(fmaxf(b, 1e-4f), 1.0f - 1e-4f);
}

// argmax over q == argmax over clip(beta) (monotone). Positive-float bits are
// order-preserving; ~n breaks ties toward smaller n (jnp.argmax semantics).
__device__ __forceinline__ unsigned long long mkkey(float bf, unsigned n) {
    unsigned hi = __float_as_uint(clipb(bf));
    return ((unsigned long long)hi << 32) |
           (unsigned long long)(0xFFFFFFFFu - n);
}

// Per-block LDS argmax -> plain-store partials. No memset needed, no global
// atomics. Also zeroes the last-block counter for k_main (stream order
// guarantees this lands before any k_main increment).
__global__ void __launch_bounds__(256) k_argmax(
    const float4* __restrict__ beta4, const int4* __restrict__ tidx4,
    unsigned long long* __restrict__ pk_part, unsigned int* __restrict__ cnt) {
    int b = blockIdx.y;
    __shared__ unsigned long long smax[KK];
    for (int t = threadIdx.x; t < KK; t += 256) smax[t] = 0ULL;
    if (blockIdx.x == 0 && b == 0 && threadIdx.x == 0) *cnt = 0u;
    __syncthreads();
    const float4* b4 = beta4 + (size_t)b * (NN / 4);
    const int4*   t4 = tidx4 + (size_t)b * (NN / 4);
    for (int i = blockIdx.x * 256 + threadIdx.x; i < NN / 4; i += PB * 256) {
        float4 bv = b4[i];
        int4   tv = t4[i];
        unsigned n0 = 4u * (unsigned)i;
        if (tv.x > 0) atomicMax(&smax[tv.x - 1], mkkey(bv.x, n0));
        if (tv.y > 0) atomicMax(&smax[tv.y - 1], mkkey(bv.y, n0 + 1));
        if (tv.z > 0) atomicMax(&smax[tv.z - 1], mkkey(bv.z, n0 + 2));
        if (tv.w > 0) atomicMax(&smax[tv.w - 1], mkkey(bv.w, n0 + 3));
    }
    __syncthreads();
    if (threadIdx.x < KK)
        pk_part[((size_t)b * PB + blockIdx.x) * KK + threadIdx.x] =
            smax[threadIdx.x];
}

__global__ void __launch_bounds__(HB) k_main(
    const float*  __restrict__ beta, const float2* __restrict__ cc,
    const float*  __restrict__ pe,   const float2* __restrict__ pp,
    const float*  __restrict__ pt,   const float*  __restrict__ te,
    const float2* __restrict__ tp,   const float*  __restrict__ tt,
    const int*    __restrict__ tidx,
    const unsigned long long* __restrict__ pk_part,
    unsigned long long* __restrict__ final_packed,
    float* __restrict__ part, unsigned int* __restrict__ cnt,
    float* __restrict__ out) {
    int b = blockIdx.y;
    // SoA condensation points: pair-readable as v2f (ds_read_b64 broadcast)
    __shared__ v2f sox[KK / 2];   // x_alpha
    __shared__ v2f soy[KK / 2];   // y_alpha
    __shared__ v2f soq[KK / 2];   // q_alpha * exf
    __shared__ float sred[8][8];
    __shared__ unsigned s_last;
    float* sax = (float*)sox;
    float* say = (float*)soy;
    float* saq = (float*)soq;

    // reduce argmax partials (L2-hot) -> decode condensation points
    if (threadIdx.x < KK) {
        const unsigned long long* src =
            pk_part + ((size_t)b * PB) * KK + threadIdx.x;
        unsigned long long v = 0ULL;
        #pragma unroll 8
        for (int pb = 0; pb < PB; ++pb) {
            unsigned long long u = src[(size_t)pb * KK];
            v = (u > v) ? u : v;
        }
        if (blockIdx.x == 0) final_packed[b * KK + threadIdx.x] = v;
        float x = 0.f, y = 0.f, qz = 0.f;
        if (v) {
            unsigned n = 0xFFFFFFFFu - (unsigned)(v & 0xFFFFFFFFu);
            float ba = __uint_as_float((unsigned)(v >> 32));  // clip(beta_alpha)
            float at = atanhf(ba);
            float2 c = cc[b * NN + (int)n];
            x = c.x; y = c.y; qz = at * at + 0.5f;            // Q_MIN = 0.5
        }
        sax[threadIdx.x] = x;
        say[threadIdx.x] = y;
        saq[threadIdx.x] = qz;
    }

    int base = blockIdx.x * (HB * HH) + threadIdx.x;
    bool vv[HH]; int ii[HH]; float rp[HH];
    v2f cx2[HH], cy2[HH];
    #pragma unroll
    for (int h = 0; h < HH; ++h) {
        int n = base + h * HB;
        vv[h] = n < NN;
        ii[h] = b * NN + (vv[h] ? n : 0);
        float2 c = cc[ii[h]];
        cx2[h].x = c.x; cx2[h].y = c.x;
        cy2[h].x = c.y; cy2[h].y = c.y;
        rp[h] = 0.f;
    }
    __syncthreads();

    const v2f eps2 = {1e-12f, 1e-12f};
    const v2f one2 = {1.0f, 1.0f};
    const v2f zero2 = {0.0f, 0.0f};

    // two objects per iteration: packed-f32 (v_pk_*) dual-rate VALU.
    // rp accumulated in ascending-k order with scalar fmas.
    // 2 waves/SIMD: one wave's pk ops overlap the other wave's v_sqrt.
    #pragma unroll 2
    for (int k2 = 0; k2 < KK / 2; ++k2) {
        v2f ox = sox[k2], oy = soy[k2], oq = soq[k2];   // uniform -> broadcast
        #pragma unroll
        for (int h = 0; h < HH; ++h) {
            v2f dx = cx2[h] - ox;
            v2f dy = cy2[h] - oy;
            v2f s  = FMA2(dx, dx, FMA2(dy, dy, eps2));
            v2f d;
            d.x = __builtin_amdgcn_sqrtf(s.x);          // raw v_sqrt_f32
            d.y = __builtin_amdgcn_sqrtf(s.y);
            v2f r = MAX2(one2 - d, zero2);
            rp[h] = fmaf(oq.x, r.x, rp[h]);             // k = 2*k2
            rp[h] = fmaf(oq.y, r.y, rp[h]);             // k = 2*k2+1
        }
    }

    float p_att = 0.f, p_rep = 0.f, p_nb = 0.f, p_nc = 0.f;
    float p_ps = 0.f, p_e = 0.f, p_pos = 0.f, p_tm = 0.f;

    #pragma unroll
    for (int h = 0; h < HH; ++h) {
        if (!vv[h]) continue;
        int   idx = ii[h];
        float rep = rp[h];
        float bc  = clipb(beta[idx]);
        float at  = atanhf(bc);
        float at2 = at * at;
        float q   = at2 + 0.5f;
        int   ti  = tidx[idx];
        int   obj = ti - 1;

        if (obj >= 0) {                     // member: move own term rep -> att
            float ox = sax[obj], oy = say[obj], oqz = saq[obj];
            float dx = cx2[h].x - ox, dy = cy2[h].x - oy;
            float s = fmaf(dx, dx, fmaf(dy, dy, 1e-12f));
            float d = __builtin_amdgcn_sqrtf(s);
            rep   -= oqz * fmaxf(1.0f - d, 0.0f);
            p_att += q * (oqz * s);         // dist^2 == s (incl. 1e-12 eps)
        }
        p_rep += q * rep;

        if (ti == 0) {                      // noise hit
            p_nb += bc;
            p_nc += 1.0f;
        } else {                            // payload (beta-weighted, non-noise)
            p_ps += at2;
            float de = pe[idx] - te[idx];
            float a  = fabsf(de);
            float hb = (a <= 2.0f) ? (0.5f * de * de) : (2.0f * (a - 1.0f));
            p_e  += at2 * hb;
            float2 ppv = pp[idx], tpv = tp[idx];
            float dpx = ppv.x - tpv.x, dpy = ppv.y - tpv.y;
            p_pos += at2 * (dpx * dpx + dpy * dpy);
            float dt = pt[idx] - tt[idx];
            p_tm += at2 * dt * dt;
        }
    }

    float vals[8] = {p_att, p_rep, p_nb, p_nc, p_ps, p_e, p_pos, p_tm};
    int lane = threadIdx.x & 63, wave = threadIdx.x >> 6;
    #pragma unroll
    for (int i = 0; i < 8; ++i) {
        float v = vals[i];
        #pragma unroll
        for (int off = 32; off > 0; off >>= 1) v += __shfl_down(v, off, 64);
        if (lane == 0) sred[wave][i] = v;
    }
    __syncthreads();
    if (threadIdx.x < 8) {
        float s = 0.f;
        #pragma unroll
        for (int w = 0; w < HB / 64; ++w) s += sred[w][threadIdx.x];
        part[(b * GX + blockIdx.x) * 8 + threadIdx.x] = s;   // plain store
    }
    __syncthreads();

    // last-block-done: release our part row, count, last block finalizes
    if (threadIdx.x == 0) {
        __threadfence();                                  // device-scope release
        unsigned prev = atomicAdd(cnt, 1u);               // device-scope
        s_last = (prev == (unsigned)(NBLK - 1)) ? 1u : 0u;
    }
    __syncthreads();
    if (s_last) {
        __threadfence();                                  // device-scope acquire
        if (threadIdx.x < 64) {
            int flane = threadIdx.x;

            // beta_alpha / n_obj terms straight from the reduced keys
            float nobj = 0.f, sba = 0.f;
            for (int t = flane; t < BB * KK; t += 64) {
                unsigned long long v = final_packed[t];
                if (v) {
                    nobj += 1.f;
                    sba  += 1.0f - __uint_as_float((unsigned)(v >> 32));
                }
            }
            #pragma unroll
            for (int off = 32; off > 0; off >>= 1) {
                nobj += __shfl_xor(nobj, off, 64);
                sba  += __shfl_xor(sba, off, 64);
            }

            // lane L sums component (L&7) over rows (L>>3)+8j (coalesced)
            int comp = flane & 7;
            float v = 0.f;
            for (int r = flane >> 3; r < NBLK; r += 8)
                v += part[r * 8 + comp];
            v += __shfl_xor(v, 8, 64);
            v += __shfl_xor(v, 16, 64);
            v += __shfl_xor(v, 32, 64);      // lane c (c<8) holds total of comp c
            float tot[8];
            #pragma unroll
            for (int c = 0; c < 8; ++c) tot[c] = __shfl(v, c, 64);

            if (flane == 0) {
                float inv_n  = 1.0f / (float)(BB * NN);
                float L_beta = sba / fmaxf(nobj, 1.0f) +
                               tot[2] / fmaxf(tot[3], 1.0f);      // S_B = 1
                float p_sum  = fmaxf(tot[4], 1e-6f);
                out[0] = tot[0] * inv_n + tot[1] * inv_n + L_beta +
                         (tot[5] + tot[6] + tot[7]) / p_sum;
            }
        }
    }
}

extern "C" void kernel_launch(void* const* d_in, const int* in_sizes, int n_in,
                              void* d_out, int out_size, void* d_ws, size_t ws_size,
                              hipStream_t stream) {
    const float*  beta = (const float*)d_in[0];
    const float2* cc   = (const float2*)d_in[1];
    const float*  pe   = (const float*)d_in[2];
    const float2* pp   = (const float2*)d_in[3];
    const float*  pt   = (const float*)d_in[4];
    const float*  te   = (const float*)d_in[5];
    const float2* tp   = (const float2*)d_in[6];
    const float*  tt   = (const float*)d_in[7];
    const int*    ti   = (const int*)d_in[8];

    unsigned long long* pk_part      = (unsigned long long*)d_ws;
    unsigned long long* final_packed = (unsigned long long*)((char*)d_ws + 262144);
    float*              part         = (float*)((char*)d_ws + 266240);
    unsigned int*       cnt          = (unsigned int*)((char*)d_ws + 272512);
    float*              out          = (float*)d_out;

    k_argmax<<<dim3(PB, BB), 256, 0, stream>>>(
        (const float4*)beta, (const int4*)ti, pk_part, cnt);
    k_main<<<dim3(GX, BB), HB, 0, stream>>>(
        beta, cc, pe, pp, pt, te, tp, tt, ti,
        pk_part, final_packed, part, cnt, out);
}